// Round 2
// baseline (909.093 us; speedup 1.0000x reference)
//
#include <hip/hip_runtime.h>
#include <hip/hip_bf16.h>
#include <cstdint>

// ---------------------------------------------------------------------------
// MultiHeadSelfAttention (B=8, S=2048, D=1024, heads=1, causal) on gfx950.
// Pipeline: cast->bf16 | QKV NT-GEMMs (MFMA) | flash causal attn | out GEMM.
// ---------------------------------------------------------------------------

typedef short  bf16x8 __attribute__((ext_vector_type(8)));  // 8 bf16 = 4 VGPR
typedef float  f32x4  __attribute__((ext_vector_type(4)));

#define S_LEN 2048
#define D_DIM 1024
#define M_ROWS 16384   // B*S

__device__ __forceinline__ ushort f32_to_bf16_rne(float f) {
    uint32_t u = __float_as_uint(f);
    uint32_t r = (u + 0x7FFFu + ((u >> 16) & 1u)) >> 16;
    return (ushort)r;
}

__device__ __forceinline__ void gload_lds16(const ushort* g, ushort* l) {
    __builtin_amdgcn_global_load_lds(
        (const __attribute__((address_space(1))) uint32_t*)(const uint32_t*)(const void*)g,
        (__attribute__((address_space(3))) uint32_t*)(uint32_t*)(void*)l, 16, 0, 0);
}

// ---------------------------------------------------------------------------
// cast fp32 -> bf16, 4 elements per thread
// ---------------------------------------------------------------------------
__global__ void cast_f32_bf16(const float* __restrict__ in,
                              ushort* __restrict__ out, int n4) {
    int i = blockIdx.x * blockDim.x + threadIdx.x;
    if (i < n4) {
        float4 v = ((const float4*)in)[i];
        ushort4 o;
        o.x = f32_to_bf16_rne(v.x);
        o.y = f32_to_bf16_rne(v.y);
        o.z = f32_to_bf16_rne(v.z);
        o.w = f32_to_bf16_rne(v.w);
        ((ushort4*)out)[i] = o;
    }
}

// ---------------------------------------------------------------------------
// NT GEMM: C[i,j] = sum_k A[i,k] * B[j,k];  A [M][1024], B [N][1024] bf16.
// 128x128 tile, BK=32, 4 waves (2x2), each wave 64x64 via 4x4 MFMA frags.
// MODE 0: C bf16 row-major [M][1024]
// MODE 1: C bf16 transposed per batch: Vt[b][j][s]  (b=i>>11, s=i&2047)
// MODE 2: C fp32 row-major [M][1024]
// Operands swapped in MFMA so each lane holds 1 row x 4 consecutive cols.
// ---------------------------------------------------------------------------
template <int MODE>
__global__ __launch_bounds__(256)
void gemm_bt(const ushort* __restrict__ A, const ushort* __restrict__ B,
             void* __restrict__ C) {
    __shared__ ushort As[128 * 32];
    __shared__ ushort Bs[128 * 32];

    const int t  = threadIdx.x;
    const int tm = blockIdx.x;      // M tile (128 rows)
    const int tn = blockIdx.y;      // N tile (128 cols)
    const int l  = t & 63;
    const int w  = t >> 6;
    const int wr = w >> 1, wc = w & 1;
    const int lr = l & 15;
    const int lk = (l >> 4) << 3;

    f32x4 acc[4][4] = {};

    const int arow = t >> 2;
    const int akc  = (t & 3) << 3;
    const ushort* Ag = A + (size_t)(tm * 128 + arow) * D_DIM + akc;
    const ushort* Bg = B + (size_t)(tn * 128 + arow) * D_DIM + akc;
    ushort* Al = &As[arow * 32 + akc];
    ushort* Bl = &Bs[arow * 32 + akc];

    for (int k0 = 0; k0 < D_DIM; k0 += 32) {
        __syncthreads();
        gload_lds16(Ag + k0,               Al);
        gload_lds16(Ag + k0 + 64 * D_DIM,  Al + 64 * 32);
        gload_lds16(Bg + k0,               Bl);
        gload_lds16(Bg + k0 + 64 * D_DIM,  Bl + 64 * 32);
        __syncthreads();

        bf16x8 af[4], bf[4];
#pragma unroll
        for (int m = 0; m < 4; ++m)
            af[m] = *(const bf16x8*)&As[(wr * 64 + m * 16 + lr) * 32 + lk];
#pragma unroll
        for (int n = 0; n < 4; ++n)
            bf[n] = *(const bf16x8*)&Bs[(wc * 64 + n * 16 + lr) * 32 + lk];
#pragma unroll
        for (int n = 0; n < 4; ++n)
#pragma unroll
            for (int m = 0; m < 4; ++m)
                acc[n][m] = __builtin_amdgcn_mfma_f32_16x16x32_bf16(
                    bf[n], af[m], acc[n][m], 0, 0, 0);
    }

    const int cr = (l >> 4) << 2;  // register dim -> 4 consecutive cols
#pragma unroll
    for (int n = 0; n < 4; ++n) {
#pragma unroll
        for (int m = 0; m < 4; ++m) {
            const int row  = tm * 128 + wr * 64 + m * 16 + lr;
            const int col0 = tn * 128 + wc * 64 + n * 16 + cr;
            f32x4 v = acc[n][m];
            if (MODE == 0) {
                ushort4 o;
                o.x = f32_to_bf16_rne(v[0]);
                o.y = f32_to_bf16_rne(v[1]);
                o.z = f32_to_bf16_rne(v[2]);
                o.w = f32_to_bf16_rne(v[3]);
                *(ushort4*)((ushort*)C + (size_t)row * D_DIM + col0) = o;
            } else if (MODE == 2) {
                *(f32x4*)((float*)C + (size_t)row * D_DIM + col0) = v;
            } else {  // MODE 1: Vt[b][d][s]
                const int b = row >> 11;
                const int s = row & 2047;
                ushort* Vt = (ushort*)C;
                size_t base = ((size_t)b * D_DIM + col0) * S_LEN + s;
#pragma unroll
                for (int r = 0; r < 4; ++r)
                    Vt[base + (size_t)r * S_LEN] = f32_to_bf16_rne(v[r]);
            }
        }
    }
}

// ---------------------------------------------------------------------------
// Flash causal attention.  Q,K bf16 [8][2048][1024], Vt bf16 [8][1024][2048].
// Block: 512 thr (8 waves).  BQ=32 q-rows, BKV=64 kv per tile.
// Wave w owns D slice [w*128, w*128+128): partial QK^T (LDS-reduced),
// fp32 online softmax, PV accumulates O slice.  O overwrites Q buffer.
// ---------------------------------------------------------------------------
__global__ __launch_bounds__(512)
void attn_causal(const ushort* __restrict__ Q, const ushort* __restrict__ K,
                 const ushort* __restrict__ Vt, ushort* __restrict__ O) {
    __shared__ float  Sred[4][32][64];   // 32 KB partial score buffers
    __shared__ ushort P_lds[32 * 64];    // 4 KB, XOR-swizzled bf16 P
    __shared__ float  m_st[32], l_st[32], alpha_lds[32];

    const int qb = blockIdx.x;           // q tile (32 rows)
    const int b  = blockIdx.y;           // batch
    const int t  = threadIdx.x;
    const int l  = t & 63;
    const int w  = t >> 6;
    const int lr = l & 15;
    const int lk = (l >> 4) << 3;
    const int rg = (l >> 4) << 2;        // row-group base within 16
    const int ds = w << 7;               // wave's D-slice base

    if (t < 32) { m_st[t] = -1e30f; l_st[t] = 0.0f; }

    // hoist Q fragments for this wave's D slice: qf[qm][ks]
    bf16x8 qf[2][4];
    const ushort* Qb = Q + ((size_t)b * S_LEN + qb * 32) * D_DIM + ds;
#pragma unroll
    for (int qm = 0; qm < 2; ++qm)
#pragma unroll
        for (int ks = 0; ks < 4; ++ks)
            qf[qm][ks] = *(const bf16x8*)(Qb + (size_t)(qm * 16 + lr) * D_DIM +
                                          ks * 32 + lk);

    f32x4 acc_o[2][8] = {};
    __syncthreads();

    const float scale = 0.03125f;  // 1/sqrt(1024)
    const int Tlast = (qb * 32 + 31) >> 6;

    for (int tt = 0; tt <= Tlast; ++tt) {
        // ---- partial QK^T over this wave's D slice ----
        f32x4 acc_s[2][4] = {};
        const ushort* Kb = K + ((size_t)b * S_LEN + tt * 64) * D_DIM + ds;
#pragma unroll
        for (int kn = 0; kn < 4; ++kn) {
            bf16x8 bk[4];
#pragma unroll
            for (int ks = 0; ks < 4; ++ks)
                bk[ks] = *(const bf16x8*)(Kb + (size_t)(kn * 16 + lr) * D_DIM +
                                          ks * 32 + lk);
#pragma unroll
            for (int ks = 0; ks < 4; ++ks)
#pragma unroll
                for (int qm = 0; qm < 2; ++qm)
                    acc_s[qm][kn] = __builtin_amdgcn_mfma_f32_16x16x32_bf16(
                        qf[qm][ks], bk[ks], acc_s[qm][kn], 0, 0, 0);
        }

        // ---- pairwise cross-wave reduction into Sred[0..3] ----
        if (w >= 4) {
#pragma unroll
            for (int qm = 0; qm < 2; ++qm)
#pragma unroll
                for (int kn = 0; kn < 4; ++kn)
#pragma unroll
                    for (int r = 0; r < 4; ++r)
                        Sred[w - 4][qm * 16 + rg + r][kn * 16 + lr] =
                            acc_s[qm][kn][r];
        }
        __syncthreads();
        if (w < 4) {
#pragma unroll
            for (int qm = 0; qm < 2; ++qm)
#pragma unroll
                for (int kn = 0; kn < 4; ++kn)
#pragma unroll
                    for (int r = 0; r < 4; ++r)
                        Sred[w][qm * 16 + rg + r][kn * 16 + lr] +=
                            acc_s[qm][kn][r];
        }
        __syncthreads();

        // ---- reduce 4 partials + online softmax (thread = row x 4 cols) ----
        {
            const int row = t >> 4;
            const int ci  = (t & 15) << 2;
            f32x4 v = {};
#pragma unroll
            for (int ww = 0; ww < 4; ++ww)
                v += *(const f32x4*)&Sred[ww][row][ci];

            const int q   = qb * 32 + row;
            const int kv0 = tt * 64 + ci;
            float vv0 = (kv0 + 0 <= q) ? v[0] * scale : -1e30f;
            float vv1 = (kv0 + 1 <= q) ? v[1] * scale : -1e30f;
            float vv2 = (kv0 + 2 <= q) ? v[2] * scale : -1e30f;
            float vv3 = (kv0 + 3 <= q) ? v[3] * scale : -1e30f;

            float mx = fmaxf(fmaxf(vv0, vv1), fmaxf(vv2, vv3));
            mx = fmaxf(mx, __shfl_xor(mx, 1, 16));
            mx = fmaxf(mx, __shfl_xor(mx, 2, 16));
            mx = fmaxf(mx, __shfl_xor(mx, 4, 16));
            mx = fmaxf(mx, __shfl_xor(mx, 8, 16));

            const float mo = m_st[row];
            const float mn = fmaxf(mo, mx);
            const float al = __expf(mo - mn);

            float p0 = __expf(vv0 - mn);
            float p1 = __expf(vv1 - mn);
            float p2 = __expf(vv2 - mn);
            float p3 = __expf(vv3 - mn);
            float ps = p0 + p1 + p2 + p3;
            ps += __shfl_xor(ps, 1, 16);
            ps += __shfl_xor(ps, 2, 16);
            ps += __shfl_xor(ps, 4, 16);
            ps += __shfl_xor(ps, 8, 16);

            if ((t & 15) == 0) {
                m_st[row] = mn;
                l_st[row] = l_st[row] * al + ps;
                alpha_lds[row] = al;
            }
            ushort4 o;
            o.x = f32_to_bf16_rne(p0);
            o.y = f32_to_bf16_rne(p1);
            o.z = f32_to_bf16_rne(p2);
            o.w = f32_to_bf16_rne(p3);
            uint32_t byte = (uint32_t)(row * 64 + ci) * 2u ^
                            (uint32_t)((row & 7) << 4);
            *(ushort4*)((char*)P_lds + byte) = o;
        }
        __syncthreads();

        // ---- rescale O, read P frags, PV MFMA ----
        float av[2][4];
#pragma unroll
        for (int qm = 0; qm < 2; ++qm)
#pragma unroll
            for (int r = 0; r < 4; ++r)
                av[qm][r] = alpha_lds[qm * 16 + rg + r];
#pragma unroll
        for (int qm = 0; qm < 2; ++qm)
#pragma unroll
            for (int dn = 0; dn < 8; ++dn)
#pragma unroll
                for (int r = 0; r < 4; ++r)
                    acc_o[qm][dn][r] *= av[qm][r];

        bf16x8 pf[2][2];
#pragma unroll
        for (int qm = 0; qm < 2; ++qm)
#pragma unroll
            for (int kt = 0; kt < 2; ++kt) {
                const int prow = qm * 16 + lr;
                uint32_t byte = (uint32_t)(prow * 64 + kt * 32 + lk) * 2u ^
                                (uint32_t)((prow & 7) << 4);
                pf[qm][kt] = *(const bf16x8*)((char*)P_lds + byte);
            }

        const ushort* Vb = Vt + ((size_t)b * D_DIM + ds) * S_LEN + tt * 64;
#pragma unroll
        for (int dn = 0; dn < 8; ++dn) {
#pragma unroll
            for (int kt = 0; kt < 2; ++kt) {
                bf16x8 bv = *(const bf16x8*)(Vb +
                    (size_t)(dn * 16 + lr) * S_LEN + kt * 32 + lk);
#pragma unroll
                for (int qm = 0; qm < 2; ++qm)
                    acc_o[qm][dn] = __builtin_amdgcn_mfma_f32_16x16x32_bf16(
                        pf[qm][kt], bv, acc_o[qm][dn], 0, 0, 0);
            }
        }
    }

    // ---- epilogue: divide by l, store bf16 O (over Q buffer) ----
    float invl[2][4];
#pragma unroll
    for (int qm = 0; qm < 2; ++qm)
#pragma unroll
        for (int r = 0; r < 4; ++r)
            invl[qm][r] = 1.0f / l_st[qm * 16 + rg + r];

    ushort* Ob = O + ((size_t)b * S_LEN + qb * 32) * D_DIM + ds;
#pragma unroll
    for (int qm = 0; qm < 2; ++qm)
#pragma unroll
        for (int dn = 0; dn < 8; ++dn)
#pragma unroll
            for (int r = 0; r < 4; ++r)
                Ob[(size_t)(qm * 16 + rg + r) * D_DIM + dn * 16 + lr] =
                    f32_to_bf16_rne(acc_o[qm][dn][r] * invl[qm][r]);
}

// ---------------------------------------------------------------------------
extern "C" void kernel_launch(void* const* d_in, const int* in_sizes, int n_in,
                              void* d_out, int out_size, void* d_ws,
                              size_t ws_size, hipStream_t stream) {
    const float* x  = (const float*)d_in[0];
    const float* Wq = (const float*)d_in[1];
    const float* Wk = (const float*)d_in[2];
    const float* Wv = (const float*)d_in[3];
    const float* Wo = (const float*)d_in[4];

    char* ws = (char*)d_ws;
    size_t off = 0;
    ushort* xb  = (ushort*)(ws + off); off += (size_t)M_ROWS * D_DIM * 2;   // 32MB
    ushort* Wqb = (ushort*)(ws + off); off += (size_t)D_DIM * D_DIM * 2;    // 2MB
    ushort* Wkb = (ushort*)(ws + off); off += (size_t)D_DIM * D_DIM * 2;
    ushort* Wvb = (ushort*)(ws + off); off += (size_t)D_DIM * D_DIM * 2;
    ushort* Wob = (ushort*)(ws + off); off += (size_t)D_DIM * D_DIM * 2;
    ushort* Qb  = (ushort*)(ws + off); off += (size_t)M_ROWS * D_DIM * 2;   // -> O
    ushort* Kb  = (ushort*)(ws + off); off += (size_t)M_ROWS * D_DIM * 2;
    ushort* Vtb = (ushort*)(ws + off); off += (size_t)M_ROWS * D_DIM * 2;

    // casts
    cast_f32_bf16<<<(M_ROWS * D_DIM / 4 + 255) / 256, 256, 0, stream>>>(
        x, xb, M_ROWS * D_DIM / 4);
    cast_f32_bf16<<<(D_DIM * D_DIM / 4 + 255) / 256, 256, 0, stream>>>(
        Wq, Wqb, D_DIM * D_DIM / 4);
    cast_f32_bf16<<<(D_DIM * D_DIM / 4 + 255) / 256, 256, 0, stream>>>(
        Wk, Wkb, D_DIM * D_DIM / 4);
    cast_f32_bf16<<<(D_DIM * D_DIM / 4 + 255) / 256, 256, 0, stream>>>(
        Wv, Wvb, D_DIM * D_DIM / 4);
    cast_f32_bf16<<<(D_DIM * D_DIM / 4 + 255) / 256, 256, 0, stream>>>(
        Wo, Wob, D_DIM * D_DIM / 4);

    // QKV projections
    dim3 gg(M_ROWS / 128, D_DIM / 128);
    gemm_bt<0><<<gg, 256, 0, stream>>>(xb, Wqb, Qb);
    gemm_bt<0><<<gg, 256, 0, stream>>>(xb, Wkb, Kb);
    gemm_bt<1><<<gg, 256, 0, stream>>>(xb, Wvb, Vtb);

    // flash causal attention (O overwrites Qb)
    attn_causal<<<dim3(S_LEN / 32, 8), 512, 0, stream>>>(Qb, Kb, Vtb, Qb);

    // output projection -> fp32 d_out
    gemm_bt<2><<<gg, 256, 0, stream>>>(Qb, Wob, (float*)d_out);
}

// Round 4
// 532.138 us; speedup vs baseline: 1.7084x; 1.7084x over previous
//
#include <hip/hip_runtime.h>
#include <hip/hip_bf16.h>
#include <cstdint>

// ---------------------------------------------------------------------------
// MultiHeadSelfAttention (B=8, S=2048, D=1024, heads=1, causal) on gfx950.
// Round 3 == round 2 (infra failure, resubmit): GEMM-ized attention.
// cast->bf16 | QKV NT-GEMMs | QK^T (packed triangular fp16 scores) |
// row softmax | PV GEMM | out GEMM.
// ---------------------------------------------------------------------------

typedef short    bf16x8 __attribute__((ext_vector_type(8)));
typedef _Float16 f16x8  __attribute__((ext_vector_type(8)));
typedef _Float16 f16x4  __attribute__((ext_vector_type(4)));
typedef float    f32x4  __attribute__((ext_vector_type(4)));

#define S_LEN 2048
#define D_DIM 1024
#define M_ROWS 16384        // B*S
#define NT_Q 16             // 128-row q tiles per batch
#define SLOTS 136           // NT_Q*(NT_Q+1)/2 lower-triangle tiles
#define SLOT_ELEMS 16384    // 128*128
#define PBATCH ((size_t)SLOTS * SLOT_ELEMS)

__device__ __forceinline__ ushort f32_to_bf16_rne(float f) {
    uint32_t u = __float_as_uint(f);
    uint32_t r = (u + 0x7FFFu + ((u >> 16) & 1u)) >> 16;
    return (ushort)r;
}

__device__ __forceinline__ void gload_lds16(const void* g, void* l) {
    __builtin_amdgcn_global_load_lds(
        (const __attribute__((address_space(1))) uint32_t*)(const uint32_t*)g,
        (__attribute__((address_space(3))) uint32_t*)(uint32_t*)l, 16, 0, 0);
}

// ---------------------------------------------------------------------------
__global__ void cast_f32_bf16(const float* __restrict__ in,
                              ushort* __restrict__ out, int n4) {
    int i = blockIdx.x * blockDim.x + threadIdx.x;
    if (i < n4) {
        float4 v = ((const float4*)in)[i];
        ushort4 o;
        o.x = f32_to_bf16_rne(v.x);
        o.y = f32_to_bf16_rne(v.y);
        o.z = f32_to_bf16_rne(v.z);
        o.w = f32_to_bf16_rne(v.w);
        ((ushort4*)out)[i] = o;
    }
}

// ---------------------------------------------------------------------------
// NT GEMM: C[i,j] = sum_k A[i,k]*B[j,k]; A [M][1024], B [N][1024] bf16.
// MODE 0: C bf16 row-major. MODE 1: C fp16 transposed per batch Vt[b][j][s].
// MODE 2: C fp32 row-major.
// ---------------------------------------------------------------------------
template <int MODE>
__global__ __launch_bounds__(256)
void gemm_bt(const ushort* __restrict__ A, const ushort* __restrict__ B,
             void* __restrict__ C) {
    __shared__ ushort As[128 * 32];
    __shared__ ushort Bs[128 * 32];

    const int t  = threadIdx.x;
    const int tm = blockIdx.x;
    const int tn = blockIdx.y;
    const int l  = t & 63;
    const int w  = t >> 6;
    const int wr = w >> 1, wc = w & 1;
    const int lr = l & 15;
    const int lk = (l >> 4) << 3;

    f32x4 acc[4][4] = {};

    const int arow = t >> 2;
    const int akc  = (t & 3) << 3;
    const ushort* Ag = A + (size_t)(tm * 128 + arow) * D_DIM + akc;
    const ushort* Bg = B + (size_t)(tn * 128 + arow) * D_DIM + akc;
    ushort* Al = &As[arow * 32 + akc];
    ushort* Bl = &Bs[arow * 32 + akc];

    for (int k0 = 0; k0 < D_DIM; k0 += 32) {
        __syncthreads();
        gload_lds16(Ag + k0,              Al);
        gload_lds16(Ag + k0 + 64 * D_DIM, Al + 64 * 32);
        gload_lds16(Bg + k0,              Bl);
        gload_lds16(Bg + k0 + 64 * D_DIM, Bl + 64 * 32);
        __syncthreads();

        bf16x8 af[4], bf[4];
#pragma unroll
        for (int m = 0; m < 4; ++m)
            af[m] = *(const bf16x8*)&As[(wr * 64 + m * 16 + lr) * 32 + lk];
#pragma unroll
        for (int n = 0; n < 4; ++n)
            bf[n] = *(const bf16x8*)&Bs[(wc * 64 + n * 16 + lr) * 32 + lk];
#pragma unroll
        for (int n = 0; n < 4; ++n)
#pragma unroll
            for (int m = 0; m < 4; ++m)
                acc[n][m] = __builtin_amdgcn_mfma_f32_16x16x32_bf16(
                    bf[n], af[m], acc[n][m], 0, 0, 0);
    }

    const int cr = (l >> 4) << 2;
#pragma unroll
    for (int n = 0; n < 4; ++n) {
#pragma unroll
        for (int m = 0; m < 4; ++m) {
            const int row  = tm * 128 + wr * 64 + m * 16 + lr;
            const int col0 = tn * 128 + wc * 64 + n * 16 + cr;
            f32x4 v = acc[n][m];
            if (MODE == 0) {
                ushort4 o;
                o.x = f32_to_bf16_rne(v[0]);
                o.y = f32_to_bf16_rne(v[1]);
                o.z = f32_to_bf16_rne(v[2]);
                o.w = f32_to_bf16_rne(v[3]);
                *(ushort4*)((ushort*)C + (size_t)row * D_DIM + col0) = o;
            } else if (MODE == 2) {
                *(f32x4*)((float*)C + (size_t)row * D_DIM + col0) = v;
            } else {  // MODE 1: Vt[b][d][s] fp16
                const int b = row >> 11;
                const int s = row & 2047;
                _Float16* Vt = (_Float16*)C;
                size_t base = ((size_t)b * D_DIM + col0) * S_LEN + s;
#pragma unroll
                for (int r = 0; r < 4; ++r)
                    Vt[base + (size_t)r * S_LEN] = (_Float16)v[r];
            }
        }
    }
}

// ---------------------------------------------------------------------------
// QK^T over lower-triangle 128x128 tiles. blockIdx.x = slot (0..135),
// blockIdx.y = batch. Scores scaled by 1/32, diagonal-masked, fp16, written
// to packed slot s at P + b*PBATCH + s*16384, row-major 128x128.
// ---------------------------------------------------------------------------
__global__ __launch_bounds__(256)
void gemm_qk(const ushort* __restrict__ Q, const ushort* __restrict__ K,
             _Float16* __restrict__ P) {
    __shared__ ushort As[128 * 32];
    __shared__ ushort Bs[128 * 32];

    const int b = blockIdx.y;
    const int s = blockIdx.x;
    int tm = (int)((sqrtf(8.0f * (float)s + 1.0f) - 1.0f) * 0.5f);
    while ((tm + 1) * (tm + 2) / 2 <= s) ++tm;
    while (tm * (tm + 1) / 2 > s) --tm;
    const int tn = s - tm * (tm + 1) / 2;

    const int t  = threadIdx.x;
    const int l  = t & 63;
    const int w  = t >> 6;
    const int wr = w >> 1, wc = w & 1;
    const int lr = l & 15;
    const int lk = (l >> 4) << 3;

    f32x4 acc[4][4] = {};

    const int arow = t >> 2;
    const int akc  = (t & 3) << 3;
    const ushort* Ag = Q + ((size_t)b * S_LEN + tm * 128 + arow) * D_DIM + akc;
    const ushort* Bg = K + ((size_t)b * S_LEN + tn * 128 + arow) * D_DIM + akc;
    ushort* Al = &As[arow * 32 + akc];
    ushort* Bl = &Bs[arow * 32 + akc];

    for (int k0 = 0; k0 < D_DIM; k0 += 32) {
        __syncthreads();
        gload_lds16(Ag + k0,              Al);
        gload_lds16(Ag + k0 + 64 * D_DIM, Al + 64 * 32);
        gload_lds16(Bg + k0,              Bl);
        gload_lds16(Bg + k0 + 64 * D_DIM, Bl + 64 * 32);
        __syncthreads();

        bf16x8 af[4], bf[4];
#pragma unroll
        for (int m = 0; m < 4; ++m)
            af[m] = *(const bf16x8*)&As[(wr * 64 + m * 16 + lr) * 32 + lk];
#pragma unroll
        for (int n = 0; n < 4; ++n)
            bf[n] = *(const bf16x8*)&Bs[(wc * 64 + n * 16 + lr) * 32 + lk];
#pragma unroll
        for (int n = 0; n < 4; ++n)
#pragma unroll
            for (int m = 0; m < 4; ++m)
                acc[n][m] = __builtin_amdgcn_mfma_f32_16x16x32_bf16(
                    bf[n], af[m], acc[n][m], 0, 0, 0);
    }

    _Float16* slot = P + (size_t)b * PBATCH + (size_t)s * SLOT_ELEMS;
    const int cr = (l >> 4) << 2;
    const float scale = 0.03125f;
#pragma unroll
    for (int n = 0; n < 4; ++n) {
#pragma unroll
        for (int m = 0; m < 4; ++m) {
            const int row_l  = wr * 64 + m * 16 + lr;
            const int col0_l = wc * 64 + n * 16 + cr;
            f32x4 v = acc[n][m];
            f16x4 o;
#pragma unroll
            for (int r = 0; r < 4; ++r) {
                float sv = v[r] * scale;
                if (tm == tn && (col0_l + r) > row_l) sv = -30000.0f;
                o[r] = (_Float16)sv;
            }
            *(f16x4*)(slot + (size_t)row_l * 128 + col0_l) = o;
        }
    }
}

// ---------------------------------------------------------------------------
// Row softmax over packed triangular scores, in place. One block per row.
// Row q (local) spans slots tm*(tm+1)/2 .. +tm, 128 contiguous fp16 each.
// Entire row lives in registers (<= 1 f16x8 per thread).
// ---------------------------------------------------------------------------
__global__ __launch_bounds__(256)
void softmax_rows(_Float16* __restrict__ P) {
    const int b  = blockIdx.y;
    const int q  = blockIdx.x;          // 0..2047
    const int tm = q >> 7;
    const int nchunk = (tm + 1) * 16;   // 8-elem chunks in this row
    _Float16* row = P + (size_t)b * PBATCH +
                    ((size_t)(tm * (tm + 1) / 2)) * SLOT_ELEMS +
                    (size_t)(q & 127) * 128;

    const int t = threadIdx.x;
    const bool active = t < nchunk;
    _Float16* addr = row + (size_t)(t >> 4) * SLOT_ELEMS + (t & 15) * 8;

    float v[8];
    float mx = -1e30f;
    if (active) {
        f16x8 h = *(const f16x8*)addr;
#pragma unroll
        for (int i = 0; i < 8; ++i) {
            v[i] = (float)h[i];
            mx = fmaxf(mx, v[i]);
        }
    }
    // block max
#pragma unroll
    for (int d = 1; d < 64; d <<= 1) mx = fmaxf(mx, __shfl_xor(mx, d));
    __shared__ float redm[4], reds[4];
    if ((t & 63) == 0) redm[t >> 6] = mx;
    __syncthreads();
    mx = fmaxf(fmaxf(redm[0], redm[1]), fmaxf(redm[2], redm[3]));

    float sum = 0.0f;
    if (active) {
#pragma unroll
        for (int i = 0; i < 8; ++i) {
            v[i] = __expf(v[i] - mx);
            sum += v[i];
        }
    }
#pragma unroll
    for (int d = 1; d < 64; d <<= 1) sum += __shfl_xor(sum, d);
    if ((t & 63) == 0) reds[t >> 6] = sum;
    __syncthreads();
    sum = reds[0] + reds[1] + reds[2] + reds[3];
    const float inv = 1.0f / sum;

    if (active) {
        f16x8 h;
#pragma unroll
        for (int i = 0; i < 8; ++i) h[i] = (_Float16)(v[i] * inv);
        *(f16x8*)addr = h;
    }
}

// ---------------------------------------------------------------------------
// PV GEMM: O[q][d] = sum_k P[q][k] * Vt[d][k].  P packed triangular fp16,
// Vt fp16 [b][1024][2048].  K-range = (tm+1)*128.  O bf16 row-major.
// Big tiles dispatched first (tm = 15 - (x>>3)).
// ---------------------------------------------------------------------------
__global__ __launch_bounds__(256)
void gemm_pv(const _Float16* __restrict__ P, const _Float16* __restrict__ Vt,
             ushort* __restrict__ O) {
    __shared__ _Float16 As[128 * 32];
    __shared__ _Float16 Bs[128 * 32];

    const int b  = blockIdx.y;
    const int tm = NT_Q - 1 - (blockIdx.x >> 3);
    const int dn = blockIdx.x & 7;
    const int KN = (tm + 1) * 128;

    const int t  = threadIdx.x;
    const int l  = t & 63;
    const int w  = t >> 6;
    const int wr = w >> 1, wc = w & 1;
    const int lr = l & 15;
    const int lk = (l >> 4) << 3;

    f32x4 acc[4][4] = {};

    const int arow = t >> 2;
    const int akc  = (t & 3) << 3;
    const _Float16* Prow = P + (size_t)b * PBATCH +
                           ((size_t)(tm * (tm + 1) / 2)) * SLOT_ELEMS;
    const _Float16* Vb = Vt + ((size_t)b * D_DIM + dn * 128 + arow) * S_LEN;
    _Float16* Al = &As[arow * 32 + akc];
    _Float16* Bl = &Bs[arow * 32 + akc];

    for (int k0 = 0; k0 < KN; k0 += 32) {
        const _Float16* Ag = Prow + (size_t)(k0 >> 7) * SLOT_ELEMS +
                             (size_t)arow * 128 + (k0 & 127) + akc;
        __syncthreads();
        gload_lds16(Ag,            Al);
        gload_lds16(Ag + 64 * 128, Al + 64 * 32);
        gload_lds16(Vb + k0 + akc,               Bl);
        gload_lds16(Vb + k0 + akc + 64 * S_LEN,  Bl + 64 * 32);
        __syncthreads();

        f16x8 af[4], bf[4];
#pragma unroll
        for (int m = 0; m < 4; ++m)
            af[m] = *(const f16x8*)&As[(wr * 64 + m * 16 + lr) * 32 + lk];
#pragma unroll
        for (int n = 0; n < 4; ++n)
            bf[n] = *(const f16x8*)&Bs[(wc * 64 + n * 16 + lr) * 32 + lk];
#pragma unroll
        for (int n = 0; n < 4; ++n)
#pragma unroll
            for (int m = 0; m < 4; ++m)
                acc[n][m] = __builtin_amdgcn_mfma_f32_16x16x32_f16(
                    bf[n], af[m], acc[n][m], 0, 0, 0);
    }

    const int cr = (l >> 4) << 2;
#pragma unroll
    for (int n = 0; n < 4; ++n) {
#pragma unroll
        for (int m = 0; m < 4; ++m) {
            const int row  = tm * 128 + wr * 64 + m * 16 + lr;
            const int col0 = dn * 128 + wc * 64 + n * 16 + cr;
            f32x4 v = acc[n][m];
            ushort4 o;
            o.x = f32_to_bf16_rne(v[0]);
            o.y = f32_to_bf16_rne(v[1]);
            o.z = f32_to_bf16_rne(v[2]);
            o.w = f32_to_bf16_rne(v[3]);
            *(ushort4*)(O + ((size_t)b * S_LEN + row) * D_DIM + col0) = o;
        }
    }
}

// ---------------------------------------------------------------------------
extern "C" void kernel_launch(void* const* d_in, const int* in_sizes, int n_in,
                              void* d_out, int out_size, void* d_ws,
                              size_t ws_size, hipStream_t stream) {
    const float* x  = (const float*)d_in[0];
    const float* Wq = (const float*)d_in[1];
    const float* Wk = (const float*)d_in[2];
    const float* Wv = (const float*)d_in[3];
    const float* Wo = (const float*)d_in[4];

    char* ws = (char*)d_ws;
    size_t off = 0;
    ushort*    xb  = (ushort*)(ws + off);    off += (size_t)M_ROWS * D_DIM * 2; // -> O
    ushort*    Wqb = (ushort*)(ws + off);    off += (size_t)D_DIM * D_DIM * 2;
    ushort*    Wkb = (ushort*)(ws + off);    off += (size_t)D_DIM * D_DIM * 2;
    ushort*    Wvb = (ushort*)(ws + off);    off += (size_t)D_DIM * D_DIM * 2;
    ushort*    Wob = (ushort*)(ws + off);    off += (size_t)D_DIM * D_DIM * 2;
    ushort*    Qb  = (ushort*)(ws + off);    off += (size_t)M_ROWS * D_DIM * 2;
    ushort*    Kb  = (ushort*)(ws + off);    off += (size_t)M_ROWS * D_DIM * 2;
    _Float16*  Vtb = (_Float16*)(ws + off);  off += (size_t)M_ROWS * D_DIM * 2;
    _Float16*  Pb  = (_Float16*)(ws + off);  off += (size_t)8 * PBATCH * 2;

    cast_f32_bf16<<<(M_ROWS * D_DIM / 4 + 255) / 256, 256, 0, stream>>>(
        x, xb, M_ROWS * D_DIM / 4);
    cast_f32_bf16<<<(D_DIM * D_DIM / 4 + 255) / 256, 256, 0, stream>>>(
        Wq, Wqb, D_DIM * D_DIM / 4);
    cast_f32_bf16<<<(D_DIM * D_DIM / 4 + 255) / 256, 256, 0, stream>>>(
        Wk, Wkb, D_DIM * D_DIM / 4);
    cast_f32_bf16<<<(D_DIM * D_DIM / 4 + 255) / 256, 256, 0, stream>>>(
        Wv, Wvb, D_DIM * D_DIM / 4);
    cast_f32_bf16<<<(D_DIM * D_DIM / 4 + 255) / 256, 256, 0, stream>>>(
        Wo, Wob, D_DIM * D_DIM / 4);

    dim3 gg(M_ROWS / 128, D_DIM / 128);
    gemm_bt<0><<<gg, 256, 0, stream>>>(xb, Wqb, Qb);
    gemm_bt<0><<<gg, 256, 0, stream>>>(xb, Wkb, Kb);
    gemm_bt<1><<<gg, 256, 0, stream>>>(xb, Wvb, Vtb);

    gemm_qk<<<dim3(SLOTS, 8), 256, 0, stream>>>(Qb, Kb, Pb);
    softmax_rows<<<dim3(S_LEN, 8), 256, 0, stream>>>(Pb);
    gemm_pv<<<dim3(128, 8), 256, 0, stream>>>(Pb, Vtb, xb);  // O over xb

    gemm_bt<2><<<gg, 256, 0, stream>>>(xb, Wob, (float*)d_out);
}